// Round 7
// baseline (333.712 us; speedup 1.0000x reference)
//
#include <hip/hip_runtime.h>
#include <hip/hip_bf16.h>

#define NUM_EXPERTS 8
#define MODEL_DIM 1024
#define INTER_DIM 4096
#define BM 128
#define BN 128
#define BK 32
#define TILE_ELEMS 4096  // 128 rows x 32 k, bf16

typedef __attribute__((ext_vector_type(8))) short short8;
typedef __attribute__((ext_vector_type(8))) unsigned short ushort8;
typedef __attribute__((ext_vector_type(4))) unsigned short ushort4v;
typedef __attribute__((ext_vector_type(4))) float floatx4;

__device__ __forceinline__ unsigned short f2b(float f) {
  union { float f; unsigned int u; } v; v.f = f;
  unsigned int r = v.u + 0x7fffu + ((v.u >> 16) & 1u);
  return (unsigned short)(r >> 16);
}

// async 16B/lane global->LDS (DMA). LDS dest: wave-uniform base + lane*16B; global src per-lane.
#define GLOAD16(g, l)                                                                   \
  __builtin_amdgcn_global_load_lds((const __attribute__((address_space(1))) unsigned int*)(g), \
                                   (__attribute__((address_space(3))) unsigned int*)(l), 16, 0, 0)

// ---------------- router: top-2 expert ids per token ----------------
__global__ __launch_bounds__(64) void router_kernel(const float* __restrict__ x,
                                                    const float* __restrict__ gw,
                                                    int* __restrict__ eids, int T) {
  int t = blockIdx.x;
  int lane = threadIdx.x;
  float acc[NUM_EXPERTS];
#pragma unroll
  for (int e = 0; e < NUM_EXPERTS; ++e) acc[e] = 0.f;
  const float* xr = x + (size_t)t * MODEL_DIM;
#pragma unroll 4
  for (int i = lane; i < MODEL_DIM; i += 64) {
    float xv = xr[i];
#pragma unroll
    for (int e = 0; e < NUM_EXPERTS; ++e) acc[e] += xv * gw[e * MODEL_DIM + i];
  }
#pragma unroll
  for (int e = 0; e < NUM_EXPERTS; ++e) {
    float v = acc[e];
#pragma unroll
    for (int off = 32; off > 0; off >>= 1) v += __shfl_xor(v, off);
    acc[e] = v;
  }
  if (lane == 0) {
    int e0 = 0; float b0 = acc[0];
#pragma unroll
    for (int e = 1; e < NUM_EXPERTS; ++e) if (acc[e] > b0) { b0 = acc[e]; e0 = e; }
    int e1 = -1; float b1 = -3.4e38f;
#pragma unroll
    for (int e = 0; e < NUM_EXPERTS; ++e) if (e != e0 && acc[e] > b1) { b1 = acc[e]; e1 = e; }
    eids[t] = e0;
    eids[T + t] = e1;
  }
}

__global__ void hist_kernel(const int* __restrict__ eids, int* __restrict__ counts, int total) {
  int i = blockIdx.x * blockDim.x + threadIdx.x;
  if (i < total) atomicAdd(&counts[eids[i]], 1);
}

// exclusive prefix + 128-aligned padded prefix
__global__ void offsets_kernel(const int* __restrict__ counts, int* __restrict__ offsets,
                               int* __restrict__ cursor, int* __restrict__ poff) {
  if (threadIdx.x == 0 && blockIdx.x == 0) {
    int s = 0, ps = 0;
    for (int e = 0; e < NUM_EXPERTS; ++e) {
      offsets[e] = s; cursor[e] = s; poff[e] = ps;
      s += counts[e];
      ps += ((counts[e] + 127) >> 7) << 7;
    }
    offsets[NUM_EXPERTS] = s;
    poff[NUM_EXPERTS] = ps;
  }
}

__global__ void scatter_kernel(const int* __restrict__ eids, int* __restrict__ cursor,
                               int* __restrict__ token_list, int T) {
  int i = blockIdx.x * blockDim.x + threadIdx.x;
  if (i < 2 * T) {
    int e = eids[i];
    int pos = atomicAdd(&cursor[e], 1);
    int t = (i >= T) ? (i - T) : i;
    token_list[pos] = t;
  }
}

// ---------------- fused gather + fp32->bf16 + tile-pack of routed A rows ----------
// xg tiles: [p/128][kb(32)][128][32], p = padded routed row. Zero-fills pad rows.
__global__ __launch_bounds__(256) void gather_tile_kernel(
    const float* __restrict__ X, const int* __restrict__ offsets,
    const int* __restrict__ poff, const int* __restrict__ token_list,
    unsigned short* __restrict__ xg) {
  const int tid = threadIdx.x;
  const int p = blockIdx.x * 8 + (tid >> 5);   // padded row
  const int kb = tid & 31;                     // one 32-elem k chunk
  if (p >= poff[NUM_EXPERTS]) return;
  int e = 0;
#pragma unroll
  for (int q = 1; q < NUM_EXPERTS; ++q) if (p >= poff[q]) e = q;
  const int local = p - poff[e];
  const int cnt = offsets[e + 1] - offsets[e];
  unsigned short* dst = xg + ((size_t)(p >> 7) * 32 + kb) * TILE_ELEMS + (p & 127) * 32;
  if (local < cnt) {
    const int tok = token_list[offsets[e] + local];
    const float* src = X + (size_t)tok * MODEL_DIM + kb * 32;
#pragma unroll
    for (int c = 0; c < 4; ++c) {
      float4 v0 = *(const float4*)(src + c * 8);
      float4 v1 = *(const float4*)(src + c * 8 + 4);
      ushort8 s;
      s[0] = f2b(v0.x); s[1] = f2b(v0.y); s[2] = f2b(v0.z); s[3] = f2b(v0.w);
      s[4] = f2b(v1.x); s[5] = f2b(v1.y); s[6] = f2b(v1.z); s[7] = f2b(v1.w);
      *(ushort8*)(dst + c * 8) = s;
    }
  } else {
    const ushort8 z = {0, 0, 0, 0, 0, 0, 0, 0};
#pragma unroll
    for (int c = 0; c < 4; ++c) *(ushort8*)(dst + c * 8) = z;
  }
}

// ---------------- W [E][K][N] fp32 -> tile-major transposed bf16 ----------------
// out tiles: [(e*NB + n/128)*KB + k/32][128][32], NB=N/128, KB=K/32
__global__ __launch_bounds__(256) void wconv_kernel(const float* __restrict__ W,
                                                    unsigned short* __restrict__ O,
                                                    int K, int N) {
  __shared__ unsigned short tile[64 * 68];
  const int e = blockIdx.z;
  const int n0 = blockIdx.x * 64;
  const int k0 = blockIdx.y * 64;
  const int NB = N >> 7, KB = K >> 5;
  const float* src = W + (size_t)e * K * N;
  const int tid = threadIdx.x;
  {
    const int kr = tid >> 2;
    const int nq = (tid & 3) * 16;
    const float* p = src + (size_t)(k0 + kr) * N + n0 + nq;
#pragma unroll
    for (int j = 0; j < 4; ++j) {
      float4 v = *(const float4*)(p + j * 4);
      ushort4v s;
      s[0] = f2b(v.x); s[1] = f2b(v.y); s[2] = f2b(v.z); s[3] = f2b(v.w);
      *(ushort4v*)(&tile[kr * 68 + nq + j * 4]) = s;
    }
  }
  __syncthreads();
  {
    const int n = n0 + (tid >> 2);
    const int ks = (tid & 3) * 16;
#pragma unroll
    for (int c = 0; c < 4; ++c) {
      const int tk = k0 + ks + c * 4;
      ushort4v s;
      s[0] = tile[(ks + c * 4 + 0) * 68 + (n - n0)];
      s[1] = tile[(ks + c * 4 + 1) * 68 + (n - n0)];
      s[2] = tile[(ks + c * 4 + 2) * 68 + (n - n0)];
      s[3] = tile[(ks + c * 4 + 3) * 68 + (n - n0)];
      unsigned short* q =
          O + ((size_t)(e * NB + (n >> 7)) * KB + (tk >> 5)) * TILE_ELEMS + (n & 127) * 32 + (tk & 31);
      *(ushort4v*)q = s;
    }
  }
}

// ---------------- grouped GEMM: all-contiguous tile staging (m97 pattern) ----------
// A tiles, B tiles both [128][32] contiguous 8KB; 4x 1KB global_load_lds per wave/step.
#define STAGE(CUR, OFS) {                          \
  GLOAD16(aSrc0 + (OFS), &sA[CUR][wq0]);           \
  GLOAD16(aSrc1 + (OFS), &sA[CUR][wq1]);           \
  GLOAD16(bSrc0 + (OFS), &sB[CUR][wq0]);           \
  GLOAD16(bSrc1 + (OFS), &sB[CUR][wq1]);           \
}

template <bool UP>
__global__ __launch_bounds__(256) void moe_gemm(
    const unsigned short* __restrict__ A,    // UP: xg tiles; DOWN: h tiles
    const unsigned short* __restrict__ Bw,   // wT tiles
    unsigned short* __restrict__ Hout,       // UP: h tiles out
    float* __restrict__ Out,                 // DOWN: atomic fp32
    const int* __restrict__ offsets,
    const int* __restrict__ poff,
    const int* __restrict__ token_list) {
  constexpr int NSTEP = 32;  // K-chunk 1024 per block

  // XCD-chunked decode: expert = b&7 (one expert per XCD chunk)
  const int b = blockIdx.x;
  const int e = b & 7;
  const int rem = b >> 3;  // 0..1023
  int m_idx, n_idx, ks;
  if constexpr (UP) {
    m_idx = rem & 31;   // m fastest: B-panel reuse on same XCD L2
    n_idx = rem >> 5;
    ks = 0;
  } else {
    n_idx = rem & 7;    // n fastest: A-panel reuse
    m_idx = (rem >> 3) & 31;
    ks = rem >> 8;      // split-K=4
  }

  const int off = offsets[e];
  const int cnt = offsets[e + 1] - off;
  const int m0 = m_idx * BM;
  if (m0 >= cnt) return;
  const int n0 = n_idx * BN;
  const int pm0 = poff[e] + m0;  // 128-aligned padded row base

  __shared__ unsigned short sA[2][BM * BK];
  __shared__ unsigned short sB[2][BN * BK];

  const int tid = threadIdx.x;
  const int lane = tid & 63;
  const int w = tid >> 6;
  const int wm = w >> 1, wn = w & 1;
  const int fr = lane & 15;
  const int koff = (lane >> 4) * 8;
  const int wq0 = w * 1024;
  const int wq1 = w * 1024 + 512;

  // contiguous tile sources (per-lane +lane*16B)
  const unsigned short* aSrc0;
  const unsigned short* bSrc0;
  if constexpr (UP) {
    aSrc0 = A + ((size_t)(pm0 >> 7) * 32) * TILE_ELEMS + wq0 + lane * 8;
    bSrc0 = Bw + ((size_t)(e * 32 + n_idx) * 32) * TILE_ELEMS + wq0 + lane * 8;
  } else {
    aSrc0 = A + ((size_t)(pm0 >> 7) * 128 + ks * 32) * TILE_ELEMS + wq0 + lane * 8;
    bSrc0 = Bw + ((size_t)(e * 8 + n_idx) * 128 + ks * 32) * TILE_ELEMS + wq0 + lane * 8;
  }
  const unsigned short* aSrc1 = aSrc0 + 512;
  const unsigned short* bSrc1 = bSrc0 + 512;

  floatx4 acc[4][4];
  const floatx4 zero = {0.f, 0.f, 0.f, 0.f};
#pragma unroll
  for (int i = 0; i < 4; ++i)
#pragma unroll
    for (int j = 0; j < 4; ++j) acc[i][j] = zero;

  STAGE(0, 0)
  __syncthreads();

  int cur = 0;
  for (int s = 0; s < NSTEP; ++s) {
    if (s + 1 < NSTEP) STAGE(cur ^ 1, (s + 1) * TILE_ELEMS)

    short8 a[4], bfr[4];
#pragma unroll
    for (int i = 0; i < 4; ++i)
      a[i] = *(const short8*)(&sA[cur][(wm * 64 + i * 16 + fr) * BK + koff]);
#pragma unroll
    for (int j = 0; j < 4; ++j)
      bfr[j] = *(const short8*)(&sB[cur][(wn * 64 + j * 16 + fr) * BK + koff]);
#pragma unroll
    for (int i = 0; i < 4; ++i)
#pragma unroll
      for (int j = 0; j < 4; ++j)
        acc[i][j] = __builtin_amdgcn_mfma_f32_16x16x32_bf16(a[i], bfr[j], acc[i][j], 0, 0, 0);

    __syncthreads();
    cur ^= 1;
  }

  // epilogue: C/D layout col=lane&15, row=(lane>>4)*4+j
  const int rbase = wm * 64 + (lane >> 4) * 4;
  const int cbase = wn * 64 + fr;
#pragma unroll
  for (int fm = 0; fm < 4; ++fm) {
#pragma unroll
    for (int fn = 0; fn < 4; ++fn) {
#pragma unroll
      for (int j = 0; j < 4; ++j) {
        const int r = rbase + fm * 16 + j;
        const int c = cbase + fn * 16;
        if (m0 + r < cnt) {
          if constexpr (UP) {
            // h tiles: [(pm0>>7)*128 + (n0+c)/32][r][ (n0+c)%32 ]
            const int gc = n0 + c;
            Hout[((size_t)(pm0 >> 7) * 128 + (gc >> 5)) * TILE_ELEMS + r * 32 + (gc & 31)] =
                f2b(acc[fm][fn][j]);
          } else {
            const int t = token_list[off + m0 + r];
            atomicAdd(&Out[(size_t)t * MODEL_DIM + n0 + c], acc[fm][fn][j]);
          }
        }
      }
    }
  }
}

extern "C" void kernel_launch(void* const* d_in, const int* in_sizes, int n_in,
                              void* d_out, int out_size, void* d_ws, size_t ws_size,
                              hipStream_t stream) {
  const float* x = (const float*)d_in[0];
  const float* gw = (const float*)d_in[1];
  const float* w_up = (const float*)d_in[2];
  const float* w_down = (const float*)d_in[3];
  float* out = (float*)d_out;

  const int T = in_sizes[0] / MODEL_DIM;  // 2048
  const int total = 2 * T;                // 4096 routed rows

  char* wsb = (char*)d_ws;
  int* eids = (int*)wsb;            // [total]
  int* counts = eids + total;       // [8]
  int* offsets = counts + 8;        // [9]
  int* cursor = offsets + 12;       // [8]
  int* poff = cursor + 8;           // [9]
  int* token_list = poff + 12;      // [total]
  unsigned short* xg = (unsigned short*)(wsb + (1 << 20));   // 10 MB: 5120 rows tiled
  unsigned short* h  = (unsigned short*)(wsb + (11 << 20));  // 40 MB: 5120 x 4096 tiled
  unsigned short* wT = (unsigned short*)(wsb + (51 << 20));  // 64 MB shared up/down

  hipMemsetAsync(counts, 0, NUM_EXPERTS * sizeof(int), stream);
  hipMemsetAsync(d_out, 0, (size_t)out_size * sizeof(float), stream);

  router_kernel<<<T, 64, 0, stream>>>(x, gw, eids, T);
  hist_kernel<<<(total + 255) / 256, 256, 0, stream>>>(eids, counts, total);
  offsets_kernel<<<1, 64, 0, stream>>>(counts, offsets, cursor, poff);
  scatter_kernel<<<(total + 255) / 256, 256, 0, stream>>>(eids, cursor, token_list, T);
  gather_tile_kernel<<<640, 256, 0, stream>>>(x, offsets, poff, token_list, xg);

  // up: W_up [8][1024][4096] -> tiled wT, then GEMM (m fastest within XCD chunk)
  wconv_kernel<<<dim3(INTER_DIM / 64, MODEL_DIM / 64, NUM_EXPERTS), 256, 0, stream>>>(
      w_up, wT, MODEL_DIM, INTER_DIM);
  moe_gemm<true><<<dim3(NUM_EXPERTS * 32 * 32), 256, 0, stream>>>(
      xg, wT, h, nullptr, offsets, poff, token_list);

  // down: W_down [8][4096][1024] -> tiled wT, then GEMM (split-K=4, n fastest)
  wconv_kernel<<<dim3(MODEL_DIM / 64, INTER_DIM / 64, NUM_EXPERTS), 256, 0, stream>>>(
      w_down, wT, INTER_DIM, MODEL_DIM);
  moe_gemm<false><<<dim3(NUM_EXPERTS * 4 * 32 * 8), 256, 0, stream>>>(
      h, wT, nullptr, out, offsets, poff, token_list);
}